// Round 3
// baseline (83.413 us; speedup 1.0000x reference)
//
#include <hip/hip_runtime.h>

#define KLEN 64
#define FCH 16            // fine chunk length (steps)
#define WARMUP 64         // S1 contraction ~0.8/step -> 0.8^64 ~ 6e-7 rel
#define WIN_FC 64         // fine chunks per S2 window (1024 steps, one wave/block)
#define WSTEPS (WIN_FC * FCH)
#define S1_INIT_V 50.0f
#define S2_INIT_V 250.0f

__device__ __forceinline__ float fpow(float x, float e) {
    // x >= 0; x==0 -> log2=-inf -> exp2=0 (exponents here are > 0)
    return exp2f(e * __log2f(x));
}
__device__ __forceinline__ float clamp01(float x) { return fminf(fmaxf(x, 0.0f), 1.0f); }
__device__ __forceinline__ float physp(const float* raw, int i, float lo, float hi) {
    return lo + (hi - lo) / (1.0f + __expf(-raw[i]));
}
__device__ __forceinline__ float wscan_incl(float x) {  // 64-lane inclusive prefix sum
    float sc = x;
#pragma unroll
    for (int o = 1; o < 64; o <<= 1) {
        float v = __shfl_up(sc, o, 64);
        if ((int)(threadIdx.x & 63) >= o) sc += v;
    }
    return sc;
}
// per-window publish tokens; a uniform poison word cannot equal BOTH for one index
__device__ __forceinline__ unsigned tok0(int w) { return 0x9E3779B9u * (unsigned)(w + 1); }
__device__ __forceinline__ unsigned tok1(int w) { return (0x85EBCA6Bu * (unsigned)(w + 7)) ^ 0xA5A5A5A5u; }

// ---- 8-step forcing group: 24 floats = 6 float4 (16B-aligned when t%8==0) ----
struct F8 { float4 v[6]; };
__device__ __forceinline__ F8 load_f8(const float* __restrict__ forc, int t) {
    const float4* p = (const float4*)(forc + 3 * t);
    F8 r;
#pragma unroll
    for (int k = 0; k < 6; ++k) r.v[k] = p[k];
    return r;
}
__device__ __forceinline__ float f4c(const float4& v, int c) {
    return c == 0 ? v.x : c == 1 ? v.y : c == 2 ? v.z : v.w;
}
__device__ __forceinline__ float f8_get(const F8& f, int i) { return f4c(f.v[i >> 2], i & 3); }

// S1-only step; shares one log2 between the two powers
#define S1_CORE(pr, pe, te, QACC)                                         \
    {                                                                     \
        float rain = (te) > Train ? (pr) : 0.0f;                          \
        float s1f = clamp01(S1 * invS1);                                  \
        float lg = __log2f(s1f);                                          \
        float e1 = (pe)*fminf(s1f * invft, 1.0f);                         \
        float qsx = rain * exp2f(b * lg);                                 \
        float q12 = ku * exp2f(cc * lg);                                  \
        float qif = ki * s1f;                                             \
        S1 = fminf(fmaxf(S1 + rain - qsx - e1 - q12 - qif, 0.0f), S1max); \
        QACC;                                                             \
    }

// ---- Single plain launch. One window (64 chunks, 1024 steps) per 64-thread block.
// A: S1 warmup+main, (q12, qsx+qif) cached in REGISTERS; publish Qw[w] + magic flags.
// spin: device-scope acquire on all windows' flags (grid=NW<=0.5*CUs, all resident).
// B: full Picard for window-start S2, block-redundant (deterministic -> identical).
// C: S2-only finish from registers; halo (prev window's last 4 chunks) from tails[].
// D: 64-tap gamma conv straight from LDS -> out.
__global__ void __launch_bounds__(64, 1) k_all(
        const float* __restrict__ forc, const float* __restrict__ raw,
        float* __restrict__ out,
        float* __restrict__ q12f, float* __restrict__ Qw, float* __restrict__ tails,
        unsigned* __restrict__ fl0, unsigned* __restrict__ fl1,
        int T, int nfine) {
    __shared__ float S2w_l[128], qbw_l[128];
    __shared__ float s2s[4 + WIN_FC];          // [0..3] halo chunk starts, [4..67] own
    __shared__ float ker[KLEN];
    __shared__ float ls[64 + WSTEPS];          // 64-sample halo + this window's runoff
    __shared__ int flag_l;

    const int lane = threadIdx.x;
    const int w = blockIdx.x;
    const int NW = gridDim.x;
    const int j = w * WIN_FC + lane;
    const bool active = j < nfine;

    const float S1max  = physp(raw, 0, 50.0f, 5000.0f);
    const float S2max  = physp(raw, 1, 100.0f, 10000.0f);
    const float f_tens = physp(raw, 2, 0.05f, 0.95f);
    const float ku     = physp(raw, 6, 0.01f, 1000.0f);
    const float cc     = physp(raw, 7, 1.0f, 20.0f);
    const float ki     = physp(raw, 11, 0.01f, 1000.0f);
    const float ks     = physp(raw, 12, 0.001f, 10000.0f);
    const float nn     = physp(raw, 13, 1.0f, 10.0f);
    const float b      = physp(raw, 18, 0.001f, 3.0f);
    const float Train  = physp(raw, 22, -2.0f, 4.0f);
    const float invS1 = 1.0f / S1max, invS2 = 1.0f / S2max, invft = 1.0f / f_tens;

    // ---- Phase A: S1 spin-up + main; per-step (q12, qsx+qif) stay in registers ----
    float q12s[FCH], qxi[FCH];
    float Q = 0.0f;
    bool full = false;
    if (active) {
        const int t0 = j * FCH;
        full = (t0 + FCH <= T);
        float S1 = S1_INIT_V;
        int ts = max(t0 - WARMUP, 0);
        int ngw = (t0 - ts) >> 3;              // multiple of 8 by construction

        F8 cur = load_f8(forc, ts);            // if ngw==0 this IS the first main group
        for (int g = 0; g < ngw; ++g) {
            F8 nxt = load_f8(forc, ts + 8 * (g + 1));  // last prefetch = first main group
#pragma unroll
            for (int s = 0; s < 8; ++s) {
                float pr = f8_get(cur, 3 * s), pe = f8_get(cur, 3 * s + 1), te = f8_get(cur, 3 * s + 2);
                S1_CORE(pr, pe, te, );
            }
            cur = nxt;
        }
        if (full) {
#pragma unroll
            for (int g = 0; g < FCH / 8; ++g) {
                F8 nxt = cur;
                if (g + 1 < FCH / 8) nxt = load_f8(forc, t0 + 8 * (g + 1));
#pragma unroll
                for (int s = 0; s < 8; ++s) {
                    float pr = f8_get(cur, 3 * s), pe = f8_get(cur, 3 * s + 1), te = f8_get(cur, 3 * s + 2);
                    S1_CORE(pr, pe, te, q12s[8 * g + s] = q12; qxi[8 * g + s] = qsx + qif; Q += q12);
                }
                cur = nxt;
            }
        } else {  // partial tail chunk: scalar guarded loads, static register indices
#pragma unroll
            for (int s = 0; s < FCH; ++s) {
                int t = t0 + s;
                q12s[s] = 0.0f; qxi[s] = 0.0f;
                if (t < T) {
                    float pr = forc[3 * t], pe = forc[3 * t + 1], te = forc[3 * t + 2];
                    S1_CORE(pr, pe, te, q12s[s] = q12; qxi[s] = qsx + qif; Q += q12);
                }
            }
        }
        q12f[j] = Q;
        // halo persistence: this window's last 4 chunks, read by block w+1
        if (full && lane >= WIN_FC - 4) {
            float4* tp = (float4*)(tails + (size_t)(w * 4 + (lane - (WIN_FC - 4))) * 32);
#pragma unroll
            for (int h = 0; h < 8; ++h)
                tp[h] = make_float4(q12s[2 * h], qxi[2 * h], q12s[2 * h + 1], qxi[2 * h + 1]);
        }
    } else {
#pragma unroll
        for (int s = 0; s < FCH; ++s) { q12s[s] = 0.0f; qxi[s] = 0.0f; }
    }
    {   // wave-reduce chunk q12 sums -> window inflow; publish (release orders prior stores)
        float sq = Q;
#pragma unroll
        for (int o = 32; o >= 1; o >>= 1) sq += __shfl_xor(sq, o, 64);
        if (lane == 0) {
            Qw[w] = sq;
            __hip_atomic_store(&fl0[w], tok0(w), __ATOMIC_RELEASE, __HIP_MEMORY_SCOPE_AGENT);
            __hip_atomic_store(&fl1[w], tok1(w), __ATOMIC_RELEASE, __HIP_MEMORY_SCOPE_AGENT);
        }
    }

    // ---- spin: wait for ALL windows' publishes (forward progress: grid fully resident) ----
    {
        bool done = false;
        while (!done) {
            bool mine = true;
            for (int ww = lane; ww < NW; ww += 64) {
                unsigned a = __hip_atomic_load(&fl0[ww], __ATOMIC_ACQUIRE, __HIP_MEMORY_SCOPE_AGENT);
                unsigned c = __hip_atomic_load(&fl1[ww], __ATOMIC_ACQUIRE, __HIP_MEMORY_SCOPE_AGENT);
                mine = mine && (a == tok0(ww)) && (c == tok1(ww));
            }
            done = (__ballot(!mine) == 0ULL);
            if (!done) __builtin_amdgcn_s_sleep(2);
        }
    }

    // ---- Phase B: Picard fixed-point (2 windows per lane), redundant per block ----
    {
        int w0 = 2 * lane, w1 = 2 * lane + 1;
        float L0 = (w0 < NW) ? (float)min(WSTEPS, T - WSTEPS * w0) : 0.0f;
        float L1 = (w1 < NW) ? (float)min(WSTEPS, T - WSTEPS * w1) : 0.0f;
        float Q0 = (w0 < NW) ? Qw[w0] : 0.0f;
        float Q1 = (w1 < NW) ? Qw[w1] : 0.0f;

        float qb0 = ks * fpow(clamp01(S2_INIT_V * invS2), nn);
        float qb1 = qb0;
        float S20 = S2_INIT_V, S21 = S2_INIT_V;
        bool ok = (NW <= 128);
        if (ok) {
            for (int it = 0; it < 12; ++it) {
                float d0 = Q0 - L0 * qb0;
                float d1 = Q1 - L1 * qb1;
                float pair = d0 + d1;
                float sc = wscan_incl(pair);
                float excl = sc - pair;
                S20 = S2_INIT_V + excl;
                S21 = S20 + d0;
                qb0 = ks * fpow(clamp01(S20 * invS2), nn);
                qb1 = ks * fpow(clamp01(S21 * invS2), nn);
            }
            bool bad = false;
            if (w0 < NW) bad |= (S20 - L0 * qb0 < 0.5f) || (S20 + Q0 > S2max - 0.5f);
            if (w1 < NW) bad |= (S21 - L1 * qb1 < 0.5f) || (S21 + Q1 > S2max - 0.5f);
            ok = (__ballot(bad) == 0ULL);
        }
        if (ok) {
            if (w0 < NW) { S2w_l[w0] = S20; qbw_l[w0] = qb0; }
            if (w1 < NW) { S2w_l[w1] = S21; qbw_l[w1] = qb1; }
            if (lane == 0) flag_l = 0;
        } else if (lane == 0) {
            // exact-ish sequential fallback (qb frozen per window) — deterministic,
            // identical in every block; only needs windows 0..w
            flag_l = 1;
            float S2 = S2_INIT_V;
            for (int ww = 0; ww <= w; ++ww) {
                float qb = ks * fpow(clamp01(S2 * invS2), nn);
                int i0 = ww * WIN_FC, i1 = min(i0 + WIN_FC, nfine);
                for (int i = i0; i < i1; ++i) {
                    int lo = i - i0;
                    if (ww == w) s2s[4 + lo] = S2;
                    if (w > 0 && ww == w - 1 && lo >= WIN_FC - 4) s2s[lo - (WIN_FC - 4)] = S2;
                    float steps = (float)min(FCH, T - FCH * i);
                    S2 = fminf(fmaxf(S2 + q12f[i] - steps * qb, 0.0f), S2max);
                }
            }
        }
    }
    __syncthreads();

    // ---- per-chunk S2 starts via wave prefix of chunk q12 sums (Picard path) ----
    if (!flag_l) {
        {
            float excl = wscan_incl(Q) - Q;
            float v = S2w_l[w] + excl - qbw_l[w] * (float)(FCH * lane);
            s2s[4 + lane] = fminf(fmaxf(v, 0.0f), S2max);
        }
        if (w > 0) {  // previous window's chunks: lanes 60..63 give the 4 halo chunks
            float qh = q12f[(w - 1) * WIN_FC + lane];
            float excl = wscan_incl(qh) - qh;
            if (lane >= WIN_FC - 4) {
                float v = S2w_l[w - 1] + excl - qbw_l[w - 1] * (float)(FCH * lane);
                s2s[lane - (WIN_FC - 4)] = fminf(fmaxf(v, 0.0f), S2max);
            }
        }
    }

    // ---- routing kernel weights (all 64 lanes) ----
    {
        float delay = physp(raw, 21, 0.01f, 5.0f);  // mu_t
        float theta = fmaxf(delay, 1e-3f) * (1.0f / 2.5f);
        float tt = (float)lane + 0.5f;
        float logk = 1.5f * __logf(tt) - tt / theta;
        float m = logk;
#pragma unroll
        for (int o = 32; o >= 1; o >>= 1) m = fmaxf(m, __shfl_xor(m, o, 64));
        float e = __expf(logk - m);
        float s = e;
#pragma unroll
        for (int o = 32; o >= 1; o >>= 1) s += __shfl_xor(s, o, 64);
        ker[lane] = e / s;
    }
    if (w == 0) ls[lane] = 0.0f;  // halo before t=0
    __syncthreads();

    // ---- Phase C: S2-only finish from register (q12, qsx+qif); runoff into LDS ----
    {
        if (active) {
            float S2 = s2s[4 + lane];
            if (full) {
                float ro[FCH];
#pragma unroll
                for (int s = 0; s < FCH; ++s) {
                    float qb = ks * fpow(clamp01(S2 * invS2), nn);
                    ro[s] = qxi[s] + qb;
                    S2 = fminf(fmaxf(S2 + q12s[s] - qb, 0.0f), S2max);
                }
                float4* lp = (float4*)&ls[64 + FCH * lane];
                lp[0] = make_float4(ro[0], ro[1], ro[2], ro[3]);
                lp[1] = make_float4(ro[4], ro[5], ro[6], ro[7]);
                lp[2] = make_float4(ro[8], ro[9], ro[10], ro[11]);
                lp[3] = make_float4(ro[12], ro[13], ro[14], ro[15]);
            } else {
                int t0 = j * FCH;
#pragma unroll
                for (int s = 0; s < FCH; ++s) {
                    if (t0 + s < T) {
                        float qb = ks * fpow(clamp01(S2 * invS2), nn);
                        ls[64 + FCH * lane + s] = qxi[s] + qb;
                        S2 = fminf(fmaxf(S2 + q12s[s] - qb, 0.0f), S2max);
                    } else {
                        ls[64 + FCH * lane + s] = 0.0f;
                    }
                }
            }
        } else {
#pragma unroll
            for (int s = 0; s < FCH; ++s) ls[64 + FCH * lane + s] = 0.0f;
        }
        if (w > 0 && lane < 4) {  // halo: previous window's last 4 chunks (always full)
            float S2 = s2s[lane];
            const float4* tp = (const float4*)(tails + (size_t)((w - 1) * 4 + lane) * 32);
#pragma unroll
            for (int h = 0; h < 8; ++h) {
                float4 pv = tp[h];
                {
                    float qb = ks * fpow(clamp01(S2 * invS2), nn);
                    ls[FCH * lane + 2 * h] = pv.y + qb;
                    S2 = fminf(fmaxf(S2 + pv.x - qb, 0.0f), S2max);
                }
                {
                    float qb = ks * fpow(clamp01(S2 * invS2), nn);
                    ls[FCH * lane + 2 * h + 1] = pv.w + qb;
                    S2 = fminf(fmaxf(S2 + pv.z - qb, 0.0f), S2max);
                }
            }
        }
    }
    __syncthreads();

    // ---- Phase D: 64-tap causal conv from LDS; outputs interleaved (lane + 64*s)
    // so every LDS read is lane-consecutive (conflict-free) and stores coalesce.
    float acc[FCH];
#pragma unroll
    for (int s = 0; s < FCH; ++s) acc[s] = 0.0f;
#pragma unroll 4
    for (int m = 0; m < 64; ++m) {
        float km = ker[63 - m];
#pragma unroll
        for (int s = 0; s < FCH; ++s) acc[s] += km * ls[lane + 1 + m + 64 * s];
    }
    int tb = w * WSTEPS;
#pragma unroll
    for (int s = 0; s < FCH; ++s) {
        int t = tb + lane + 64 * s;
        if (t < T) out[t] = acc[s];
    }
}

extern "C" void kernel_launch(void* const* d_in, const int* in_sizes, int n_in,
                              void* d_out, int out_size, void* d_ws, size_t ws_size,
                              hipStream_t stream) {
    const float* forcing = (const float*)d_in[0];  // [T,3]
    const float* raw = (const float*)d_in[1];      // [29]
    float* out = (float*)d_out;
    float* ws = (float*)d_ws;

    int T = in_sizes[0] / 3;
    int nfine = (T + FCH - 1) / FCH;
    int NW = (nfine + WIN_FC - 1) / WIN_FC;
    int P = ((nfine + 7) / 8) * 8;
    int PW = ((NW + 7) / 8) * 8;

    float* q12f = ws;                          // [P]   per-chunk q12 sums
    float* Qw = q12f + P;                      // [PW]  per-window inflow
    float* tails = Qw + PW;                    // [NW*128] last-4-chunk (q12,qxi) pairs
    unsigned* fl0 = (unsigned*)(tails + (size_t)NW * 128);  // [PW] publish tokens
    unsigned* fl1 = fl0 + PW;                               // [PW]

    k_all<<<NW, 64, 0, stream>>>(forcing, raw, out, q12f, Qw, tails, fl0, fl1, T, nfine);
}

// Round 5
// 71.759 us; speedup vs baseline: 1.1624x; 1.1624x over previous
//
#include <hip/hip_runtime.h>

#define KLEN 64
#define FCH 16            // fine chunk length (steps)
#define WARMUP 64         // S1 contraction ~0.8/step -> 0.8^64 ~ 6e-7 rel
#define WIN_FC 64         // fine chunks per S2 window (1024 steps, one wave/block)
#define WSTEPS (WIN_FC * FCH)
#define S1_INIT_V 50.0f
#define S2_INIT_V 250.0f

__device__ __forceinline__ float fpow(float x, float e) {
    // x >= 0; x==0 -> log2=-inf -> exp2=0 (exponents here are > 0)
    return exp2f(e * __log2f(x));
}
__device__ __forceinline__ float clamp01(float x) { return fminf(fmaxf(x, 0.0f), 1.0f); }
__device__ __forceinline__ float physp(const float* raw, int i, float lo, float hi) {
    return lo + (hi - lo) / (1.0f + __expf(-raw[i]));
}
__device__ __forceinline__ float wscan_incl(float x) {  // 64-lane inclusive prefix sum
    float sc = x;
#pragma unroll
    for (int o = 1; o < 64; o <<= 1) {
        float v = __shfl_up(sc, o, 64);
        if ((int)(threadIdx.x & 63) >= o) sc += v;
    }
    return sc;
}

// ---- 8-step forcing group: 24 floats = 6 float4 (16B-aligned when t%8==0) ----
struct F8 { float4 v[6]; };
__device__ __forceinline__ F8 load_f8(const float* __restrict__ forc, int t) {
    const float4* p = (const float4*)(forc + 3 * t);
    F8 r;
#pragma unroll
    for (int k = 0; k < 6; ++k) r.v[k] = p[k];
    return r;
}
__device__ __forceinline__ float f4c(const float4& v, int c) {
    return c == 0 ? v.x : c == 1 ? v.y : c == 2 ? v.z : v.w;
}
__device__ __forceinline__ float f8_get(const F8& f, int i) { return f4c(f.v[i >> 2], i & 3); }

// S1-only step; shares one log2 between the two powers
#define S1_CORE(pr, pe, te, QACC)                                         \
    {                                                                     \
        float rain = (te) > Train ? (pr) : 0.0f;                          \
        float s1f = clamp01(S1 * invS1);                                  \
        float lg = __log2f(s1f);                                          \
        float e1 = (pe)*fminf(s1f * invft, 1.0f);                         \
        float qsx = rain * exp2f(b * lg);                                 \
        float q12 = ku * exp2f(cc * lg);                                  \
        float qif = ki * s1f;                                             \
        S1 = fminf(fmaxf(S1 + rain - qsx - e1 - q12 - qif, 0.0f), S1max); \
        QACC;                                                             \
    }

// ---- Kernel A: per-chunk S1 spin-up + main; persists (q12, qsx+qif) pairs so no
// ---- later kernel ever re-simulates S1. One window (64 chunks) per 64-thread block.
__global__ void __launch_bounds__(64) k_a(
        const float* __restrict__ forc, const float* __restrict__ raw,
        float* __restrict__ qx2, float* __restrict__ q12f, float* __restrict__ Qw,
        int T, int nfine) {
    const int lane = threadIdx.x;
    const int j = blockIdx.x * WIN_FC + lane;
    const bool active = j < nfine;

    const float S1max  = physp(raw, 0, 50.0f, 5000.0f);
    const float f_tens = physp(raw, 2, 0.05f, 0.95f);
    const float ku     = physp(raw, 6, 0.01f, 1000.0f);
    const float cc     = physp(raw, 7, 1.0f, 20.0f);
    const float ki     = physp(raw, 11, 0.01f, 1000.0f);
    const float b      = physp(raw, 18, 0.001f, 3.0f);
    const float Train  = physp(raw, 22, -2.0f, 4.0f);
    const float invS1 = 1.0f / S1max, invft = 1.0f / f_tens;

    float Q = 0.0f;
    if (active) {
        const int t0 = j * FCH;
        const bool full = (t0 + FCH <= T);
        float S1 = S1_INIT_V;
        int ts = max(t0 - WARMUP, 0);
        int ngw = (t0 - ts) >> 3;              // multiple of 8 by construction

        F8 cur = load_f8(forc, ts);            // if ngw==0 this IS the first main group
        for (int g = 0; g < ngw; ++g) {
            F8 nxt = load_f8(forc, ts + 8 * (g + 1));  // last prefetch = first main group
#pragma unroll
            for (int s = 0; s < 8; ++s) {
                float pr = f8_get(cur, 3 * s), pe = f8_get(cur, 3 * s + 1), te = f8_get(cur, 3 * s + 2);
                S1_CORE(pr, pe, te, );
            }
            cur = nxt;
        }
        if (full) {
            float4* qp = (float4*)(qx2 + 32 * j);
#pragma unroll
            for (int g = 0; g < FCH / 8; ++g) {
                F8 nxt = cur;
                if (g + 1 < FCH / 8) nxt = load_f8(forc, t0 + 8 * (g + 1));
                float pg[16];
#pragma unroll
                for (int s = 0; s < 8; ++s) {
                    float pr = f8_get(cur, 3 * s), pe = f8_get(cur, 3 * s + 1), te = f8_get(cur, 3 * s + 2);
                    S1_CORE(pr, pe, te, pg[2 * s] = q12; pg[2 * s + 1] = qsx + qif; Q += q12);
                }
                qp[4 * g + 0] = make_float4(pg[0], pg[1], pg[2], pg[3]);
                qp[4 * g + 1] = make_float4(pg[4], pg[5], pg[6], pg[7]);
                qp[4 * g + 2] = make_float4(pg[8], pg[9], pg[10], pg[11]);
                qp[4 * g + 3] = make_float4(pg[12], pg[13], pg[14], pg[15]);
                cur = nxt;
            }
        } else {  // partial tail chunk: scalar guarded loads, zero-padded pairs
#pragma unroll
            for (int s = 0; s < FCH; ++s) {
                int t = t0 + s;
                float a0 = 0.0f, a1 = 0.0f;
                if (t < T) {
                    float pr = forc[3 * t], pe = forc[3 * t + 1], te = forc[3 * t + 2];
                    S1_CORE(pr, pe, te, a0 = q12; a1 = qsx + qif; Q += q12);
                }
                qx2[32 * j + 2 * s] = a0;
                qx2[32 * j + 2 * s + 1] = a1;
            }
        }
        q12f[j] = Q;
    }
    // wave-reduce chunk q12 sums -> window inflow (block == window)
    float sq = Q;
#pragma unroll
    for (int o = 32; o >= 1; o >>= 1) sq += __shfl_xor(sq, o, 64);
    if (lane == 0) Qw[blockIdx.x] = sq;
}

// ---- Kernel BC: one window per 64-thread block.
// B: Picard for ALL window-start S2, block-redundant (deterministic -> identical).
// C: per-chunk S2-only finish from stored (q12, qsx+qif) pairs -> global runoff.
__global__ void __launch_bounds__(64) k_bc(
        const float* __restrict__ raw, const float* __restrict__ qx2,
        const float* __restrict__ q12f, const float* __restrict__ Qw,
        float* __restrict__ runoff, int T, int nfine) {
    __shared__ float s2s[WIN_FC];   // fallback-path per-chunk starts (own window)
    __shared__ int flag_l;

    const int lane = threadIdx.x;
    const int w = blockIdx.x;
    const int NW = gridDim.x;
    const int j = w * WIN_FC + lane;

    const float S2max = physp(raw, 1, 100.0f, 10000.0f);
    const float ks    = physp(raw, 12, 0.001f, 10000.0f);
    const float nn    = physp(raw, 13, 1.0f, 10.0f);
    const float invS2 = 1.0f / S2max;

    float S2start = 0.0f;
    {   // ---- Phase B: Picard fixed-point (2 windows per lane), redundant per block ----
        int w0 = 2 * lane, w1 = 2 * lane + 1;
        float L0 = (w0 < NW) ? (float)min(WSTEPS, T - WSTEPS * w0) : 0.0f;
        float L1 = (w1 < NW) ? (float)min(WSTEPS, T - WSTEPS * w1) : 0.0f;
        float Q0 = (w0 < NW) ? Qw[w0] : 0.0f;
        float Q1 = (w1 < NW) ? Qw[w1] : 0.0f;

        float qb0 = ks * fpow(clamp01(S2_INIT_V * invS2), nn);
        float qb1 = qb0;
        float S20 = S2_INIT_V, S21 = S2_INIT_V;
        bool ok = (NW <= 128);
        if (ok) {
            for (int it = 0; it < 12; ++it) {
                float d0 = Q0 - L0 * qb0;
                float d1 = Q1 - L1 * qb1;
                float pair = d0 + d1;
                float sc = wscan_incl(pair);
                float excl = sc - pair;
                S20 = S2_INIT_V + excl;
                S21 = S20 + d0;
                qb0 = ks * fpow(clamp01(S20 * invS2), nn);
                qb1 = ks * fpow(clamp01(S21 * invS2), nn);
            }
            bool bad = false;
            if (w0 < NW) bad |= (S20 - L0 * qb0 < 0.5f) || (S20 + Q0 > S2max - 0.5f);
            if (w1 < NW) bad |= (S21 - L1 * qb1 < 0.5f) || (S21 + Q1 > S2max - 0.5f);
            ok = (__ballot(bad) == 0ULL);
        }
        if (ok) {
            if (lane == 0) flag_l = 0;
            // broadcast own window's start/qb from the owning lane (w>>1), slot (w&1)
            float S2w = __shfl((w & 1) ? S21 : S20, w >> 1, 64);
            float qbw = __shfl((w & 1) ? qb1 : qb0, w >> 1, 64);
            // per-chunk S2 start via wave prefix of chunk q12 sums
            float qo = (j < nfine) ? q12f[j] : 0.0f;
            float excl = wscan_incl(qo) - qo;
            float v = S2w + excl - qbw * (float)(FCH * lane);
            S2start = fminf(fmaxf(v, 0.0f), S2max);
        } else if (lane == 0) {
            // exact-ish sequential fallback (qb frozen per window) — deterministic,
            // identical in every block; only needs windows 0..w
            flag_l = 1;
            float S2 = S2_INIT_V;
            for (int ww = 0; ww <= w; ++ww) {
                float qb = ks * fpow(clamp01(S2 * invS2), nn);
                int i0 = ww * WIN_FC, i1 = min(i0 + WIN_FC, nfine);
                for (int i = i0; i < i1; ++i) {
                    if (ww == w) s2s[i - i0] = S2;
                    float steps = (float)min(FCH, T - FCH * i);
                    S2 = fminf(fmaxf(S2 + q12f[i] - steps * qb, 0.0f), S2max);
                }
            }
        }
    }
    __syncthreads();
    if (flag_l) S2start = s2s[lane];

    // ---- Phase C: S2-only finish from stored (q12, qsx+qif) pairs ----
    if (j < nfine) {
        float S2 = S2start;
        const float4* qp = (const float4*)(qx2 + 32 * j);
        int t0 = j * FCH;
        if (t0 + FCH <= T) {
            float ro[FCH];
#pragma unroll
            for (int h = 0; h < 8; ++h) {
                float4 pv = qp[h];
                {
                    float qb = ks * fpow(clamp01(S2 * invS2), nn);
                    ro[2 * h] = pv.y + qb;
                    S2 = fminf(fmaxf(S2 + pv.x - qb, 0.0f), S2max);
                }
                {
                    float qb = ks * fpow(clamp01(S2 * invS2), nn);
                    ro[2 * h + 1] = pv.w + qb;
                    S2 = fminf(fmaxf(S2 + pv.z - qb, 0.0f), S2max);
                }
            }
            float4* rp = (float4*)(runoff + t0);
            rp[0] = make_float4(ro[0], ro[1], ro[2], ro[3]);
            rp[1] = make_float4(ro[4], ro[5], ro[6], ro[7]);
            rp[2] = make_float4(ro[8], ro[9], ro[10], ro[11]);
            rp[3] = make_float4(ro[12], ro[13], ro[14], ro[15]);
        } else {
#pragma unroll
            for (int s = 0; s < FCH; ++s) {
                int t = t0 + s;
                if (t < T) {
                    float q12v = qx2[32 * j + 2 * s], qxiv = qx2[32 * j + 2 * s + 1];
                    float qb = ks * fpow(clamp01(S2 * invS2), nn);
                    runoff[t] = qxiv + qb;
                    S2 = fminf(fmaxf(S2 + q12v - qb, 0.0f), S2max);
                }
            }
        }
    }
}

// ---- Kernel D: causal gamma-kernel routing conv (R0's proven wide version) ----
__global__ void k_route(const float* __restrict__ runoff, const float* __restrict__ raw,
                        float* __restrict__ out, int T) {
    __shared__ float ls[256 + KLEN - 1];
    __shared__ float ker[KLEN];
    int tid = threadIdx.x;
    int base = blockIdx.x * 256;
    if (tid < 64) {  // wave 0 computes the 64-tap softmax gamma kernel
        float delay = physp(raw, 21, 0.01f, 5.0f);  // mu_t
        float theta = fmaxf(delay, 1e-3f) * (1.0f / 2.5f);
        float tt = (float)tid + 0.5f;
        float logk = 1.5f * __logf(tt) - tt / theta;
        float m = logk;
#pragma unroll
        for (int o = 32; o >= 1; o >>= 1) m = fmaxf(m, __shfl_xor(m, o, 64));
        float e = __expf(logk - m);
        float s = e;
#pragma unroll
        for (int o = 32; o >= 1; o >>= 1) s += __shfl_xor(s, o, 64);
        ker[tid] = e / s;
    }
    for (int i = tid; i < 256 + KLEN - 1; i += 256) {
        int t = base - (KLEN - 1) + i;
        ls[i] = (t >= 0 && t < T) ? runoff[t] : 0.0f;
    }
    __syncthreads();
    float acc = 0.0f;
#pragma unroll
    for (int k = 0; k < KLEN; ++k) acc += ker[k] * ls[tid + (KLEN - 1) - k];
    int t = base + tid;
    if (t < T) out[t] = acc;
}

extern "C" void kernel_launch(void* const* d_in, const int* in_sizes, int n_in,
                              void* d_out, int out_size, void* d_ws, size_t ws_size,
                              hipStream_t stream) {
    const float* forcing = (const float*)d_in[0];  // [T,3]
    const float* raw = (const float*)d_in[1];      // [29]
    float* out = (float*)d_out;
    float* ws = (float*)d_ws;

    int T = in_sizes[0] / 3;
    int nfine = (T + FCH - 1) / FCH;
    int NW = (nfine + WIN_FC - 1) / WIN_FC;
    int P = ((nfine + 7) / 8) * 8;
    int PW = ((NW + 7) / 8) * 8;

    float* qx2 = ws;                     // [P*32] interleaved (q12, qsx+qif) per step
    float* q12f = qx2 + (size_t)P * 32;  // [P]  per-chunk q12 sums
    float* Qw = q12f + P;                // [PW] per-window inflow
    float* runoff = Qw + PW;             // [T]

    k_a<<<NW, 64, 0, stream>>>(forcing, raw, qx2, q12f, Qw, T, nfine);
    k_bc<<<NW, 64, 0, stream>>>(raw, qx2, q12f, Qw, runoff, T, nfine);
    k_route<<<(T + 255) / 256, 256, 0, stream>>>(runoff, raw, out, T);
}